// Round 16
// baseline (198.247 us; speedup 1.0000x reference)
//
#include <hip/hip_runtime.h>
#include <hip/hip_bf16.h>
#include <cmath>

// Problem constants: B=8 T=512 M=64 D=1024 H=16 DFF=4096, DH=64, ROT=32, L=576
using bf16 = __hip_bfloat16;
typedef __attribute__((ext_vector_type(8))) __bf16 bf16x8;
typedef __attribute__((ext_vector_type(4))) float f32x4;

struct __align__(8) bf16x4s { bf16 a, b, c, d; };

__device__ inline void gload_lds16(const void* g, void* l) {
  __builtin_amdgcn_global_load_lds(
      (__attribute__((address_space(1))) void*)g,
      (__attribute__((address_space(3))) void*)l, 16, 0, 0);
}

__device__ inline f32x4 mfma16(bf16x8 a, bf16x8 b, f32x4 c) {
  return __builtin_amdgcn_mfma_f32_16x16x32_bf16(a, b, c, 0, 0, 0);
}

#define BAR() __builtin_amdgcn_s_barrier()
#define VMC(N) asm volatile("s_waitcnt vmcnt(" #N ")" ::: "memory")
#define LGKM0() asm volatile("s_waitcnt lgkmcnt(0)" ::: "memory")

// ---------------------------------------------------------------------------
// Common GEMM body: C = A * B^T, 256x256 tile, BK=64, 512 threads (8 waves,
// 2x4; per-wave 128x64 output). 8-phase schedule (16-MFMA quadrants),
// counted vmcnt(4) at phases 4/8 only — round-10/13 proven best.
// LDS: 8 half-slots x 16KB (2-tile ring). XOR swizzle byte^=((row&7)<<4):
// linear gload_lds dest + pre-swizzled global source; ds_reads same XOR.
// CHUNK 0: XCD regions (gx/4 x gy/2); CHUNK 1: XCD owns bx rows (split-K).
// MODE 2: bf16 out = relu(acc+bias)^2      (direct stores)
// MODE 8: bf16 partial: Out[z*zstride+r*ldo+c]  (direct stores)
// MODE 9: fused QKV: bias+RoPE+reshape+Q-scale via per-wave LDS transpose;
//         V is written TRANSPOSED directly into vt[zh][d][p] (o3).
// ---------------------------------------------------------------------------
template<int MODE, int CHUNK>
__device__ __forceinline__ void gemm_body(
    const bf16* __restrict__ A, int lda, long sA,
    const bf16* __restrict__ B, int ldb, long sB,
    const float* __restrict__ bias,
    void* __restrict__ Out,
    int K, int ldo, long zstride,
    const float* __restrict__ rtab,
    bf16* __restrict__ o1, bf16* __restrict__ o2, bf16* __restrict__ o3)
{
  __shared__ bf16 lds[65536];   // 128 KiB
  const int tid = threadIdx.x, lane = tid & 63, wid = tid >> 6;
  const int wr = wid >> 2, wc = wid & 3;       // 2x4 wave grid
  const int gx = gridDim.x;
  const int bidl = blockIdx.x + gx * blockIdx.y;
  const int xcd = bidl & 7, slot_ = bidl >> 3;
  int bx, by;
  if constexpr (CHUNK == 0) {
    const int sx = gx >> 2, sy = gridDim.y >> 1;
    bx = (xcd & 3) * sx + slot_ % sx;
    by = (xcd >> 2) * sy + slot_ / sx;
  } else {
    bx = slot_ % gx;
    by = xcd * (gridDim.y >> 3) + slot_ / gx;
  }
  const int m0 = by * 256, n0 = bx * 256;
  const int z = blockIdx.z;
  const bf16* Ab = A + (long)z * sA;
  const bf16* Bb = B + (long)z * sB;
  const int nt = K >> 6;        // even, >= 2

  f32x4 acc[8][4] = {};

  auto STAGE = [&](int par, int t, int part) {
    const bf16* src = (part < 2) ? Ab : Bb;
    const int ld = (part < 2) ? lda : ldb;
    const int rb = ((part < 2) ? m0 : n0) + (part & 1) * 128;
    const int k0 = t << 6;
    bf16* dst = &lds[(par * 4 + part) * 8192];
#pragma unroll
    for (int j = 0; j < 2; ++j) {
      int idx = j * 512 + tid;            // 0..1023 chunk of 16B
      int row = idx >> 3;                 // 0..127
      int ce = ((idx & 7) ^ (row & 7)) << 3;  // pre-swizzled source column
      gload_lds16(src + (long)(rb + row) * ld + k0 + ce, dst + idx * 8);
    }
  };
  auto load_a = [&](bf16x8 (&a_)[4][2], int par, int mh) {
#pragma unroll
    for (int mf = 0; mf < 4; ++mf)
#pragma unroll
      for (int kk = 0; kk < 2; ++kk) {
        int r = mh * 64 + mf * 16 + (lane & 15);
        int cb = (kk * 64 + ((lane >> 4) << 4)) ^ ((r & 7) << 4);
        a_[mf][kk] = *(const bf16x8*)&lds[(par * 4 + wr) * 8192 + r * 64 + (cb >> 1)];
      }
  };
  auto load_b = [&](bf16x8 (&b_)[2][2], int par, int nh) {
#pragma unroll
    for (int nf = 0; nf < 2; ++nf)
#pragma unroll
      for (int kk = 0; kk < 2; ++kk) {
        int r = (wc & 1) * 64 + (nh * 2 + nf) * 16 + (lane & 15);
        int cb = (kk * 64 + ((lane >> 4) << 4)) ^ ((r & 7) << 4);
        b_[nf][kk] = *(const bf16x8*)&lds[(par * 4 + 2 + (wc >> 1)) * 8192 + r * 64 + (cb >> 1)];
      }
  };
  // kk OUTERMOST: 8 independent MFMAs per kk (no back-to-back same-acc deps)
  auto qmfma = [&](bf16x8 (&a_)[4][2], bf16x8 (&b_)[2][2], int mh, int nh) {
    __builtin_amdgcn_s_setprio(1);
#pragma unroll
    for (int kk = 0; kk < 2; ++kk)
#pragma unroll
      for (int mf = 0; mf < 4; ++mf)
#pragma unroll
        for (int nf = 0; nf < 2; ++nf)
          acc[mh * 4 + mf][nh * 2 + nf] =
              mfma16(a_[mf][kk], b_[nf][kk], acc[mh * 4 + mf][nh * 2 + nf]);
    __builtin_amdgcn_s_setprio(0);
  };

  // prologue: tile0 {A0,A1,B0,B1}, then 1.B0, 1.A0 (stay in flight)
  STAGE(0, 0, 0); STAGE(0, 0, 1); STAGE(0, 0, 2); STAGE(0, 0, 3);
  STAGE(1, 1, 2); STAGE(1, 1, 0);
  VMC(4);
  BAR();

  const int half = nt >> 1;
  for (int i = 0; i < half; ++i) {
    const int u = 2 * i;
    const bool full = (i < half - 1);
    bf16x8 a[4][2], b0[2][2], b1[2][2];
    // ======== tile u (parity 0) ========
    load_a(a, 0, 0); load_b(b0, 0, 0);
    STAGE(1, u + 1, 3);
    BAR();
    qmfma(a, b0, 0, 0);
    BAR();
    load_b(b1, 0, 1);
    STAGE(1, u + 1, 1);
    BAR();
    qmfma(a, b1, 0, 1);
    BAR();
    load_a(a, 0, 1);
    if (full) STAGE(0, u + 2, 2);
    BAR();
    qmfma(a, b1, 1, 1);
    BAR();
    if (full) STAGE(0, u + 2, 0);
    BAR();
    qmfma(a, b0, 1, 0);
    if (full) { VMC(4); } else { VMC(0); }
    BAR();
    // ======== tile u+1 (parity 1) ========
    load_a(a, 1, 0); load_b(b0, 1, 0);
    if (full) STAGE(0, u + 2, 3);
    BAR();
    qmfma(a, b0, 0, 0);
    BAR();
    load_b(b1, 1, 1);
    if (full) STAGE(0, u + 2, 1);
    BAR();
    qmfma(a, b1, 0, 1);
    BAR();
    load_a(a, 1, 1);
    if (full) STAGE(1, u + 3, 2);
    BAR();
    qmfma(a, b1, 1, 1);
    BAR();
    if (full) STAGE(1, u + 3, 0);
    BAR();
    qmfma(a, b0, 1, 0);
    if (full) VMC(4);
    BAR();
  }

  // epilogue: C/D layout col=lane&15, row=(lane>>4)*4+j  [HW-verified m89/m91]
  const int cb0 = n0 + wc * 64 + (lane & 15);
  const int rb0 = m0 + wr * 128 + ((lane >> 4) << 2);

  if constexpr (MODE == 9) {
    // fused QKV via per-wave LDS transpose (slot is free after final BAR)
    bf16* slot = &lds[wid * 8192];
    const int l15 = lane & 15;
    const int matq = n0 >> 10;               // 0=Q 1=K 2=V
    const int hh = ((n0 & 1023) >> 6) + wc;  // head index
    const float b0v = bias[n0 + wc * 64 + l15];
    const float b1v = bias[n0 + wc * 64 + l15 + 16];
    const float b2v = bias[n0 + wc * 64 + l15 + 32];
    const float b3v = bias[n0 + wc * 64 + l15 + 48];
#pragma unroll
    for (int mf = 0; mf < 8; ++mf) {
#pragma unroll
      for (int j = 0; j < 4; ++j) {
        int lr = mf * 16 + ((lane >> 4) << 2) + j;   // local row 0..127
        float a0 = acc[mf][0][j] + b0v;
        float a1 = acc[mf][1][j] + b1v;
        float a2 = acc[mf][2][j] + b2v;
        float a3 = acc[mf][3][j] + b3v;
        if (matq < 2) {
          int rr = m0 + wr * 128 + lr;
          int p = rr % 576;
          float cs = rtab[p * 16 + l15];
          float sn = rtab[9216 + p * 16 + l15];
          float r0 = a0 * cs - a1 * sn;
          float r1 = a1 * cs + a0 * sn;
          a0 = r0; a1 = r1;
          if (matq == 0) {
            const float QS = 0.18033688011112043f;  // 0.125 * log2(e)
            a0 *= QS; a1 *= QS; a2 *= QS; a3 *= QS;
          }
        }
        int sw = (lr & 7) << 3;
        slot[lr * 64 + ((l15) ^ sw)]      = __float2bfloat16(a0);
        slot[lr * 64 + ((l15 + 16) ^ sw)] = __float2bfloat16(a1);
        slot[lr * 64 + ((l15 + 32) ^ sw)] = __float2bfloat16(a2);
        slot[lr * 64 + ((l15 + 48) ^ sw)] = __float2bfloat16(a3);
      }
    }
    __syncthreads();
    if (matq == 2) {
      // V: write TRANSPOSED into vt[zh][d][p]; d = lane, 8-p runs.
#pragma unroll
      for (int it = 0; it < 16; ++it) {
        int pr0 = it * 8;
        bf16 tmp[8] __attribute__((aligned(16)));
#pragma unroll
        for (int j = 0; j < 8; ++j)
          tmp[j] = slot[(pr0 + j) * 64 + (lane ^ ((j & 7) << 3))];
        int rr = m0 + wr * 128 + pr0;
        int b_ = rr / 576, p = rr - b_ * 576;
        int zh = b_ * 16 + hh;
        *(bf16x8*)(o3 + (long)zh * 36864 + (long)lane * 576 + p) =
            *(const bf16x8*)tmp;
      }
    } else {
#pragma unroll
      for (int it = 0; it < 16; ++it) {
        int u = it * 64 + lane;
        int r_s = u >> 3, c_s = u & 7;          // row 0..127, 8-col chunk
        int rr = m0 + wr * 128 + r_s;
        bf16x8 val = *(const bf16x8*)&slot[r_s * 64 + ((c_s ^ (r_s & 7)) << 3)];
        int b_ = rr / 576, p = rr - b_ * 576;
        int zh = b_ * 16 + hh;
        if (matq == 0) {
          if (p >= 64)
            *(bf16x8*)(o1 + ((long)zh * 512 + (p - 64)) * 64 + c_s * 8) = val;
        } else {
          *(bf16x8*)(o2 + ((long)zh * 576 + p) * 64 + c_s * 8) = val;
        }
      }
    }
  } else {
    // direct stores (round-7/10 proven form)
#pragma unroll
    for (int mf = 0; mf < 8; ++mf) {
#pragma unroll
      for (int nf = 0; nf < 4; ++nf) {
        int c = cb0 + nf * 16;
#pragma unroll
        for (int j = 0; j < 4; ++j) {
          int rr = rb0 + mf * 16 + j;
          float v = acc[mf][nf][j];
          if constexpr (MODE == 2) {
            float t2 = fmaxf(v + bias[c], 0.0f);
            ((bf16*)Out)[(long)rr * ldo + c] = __float2bfloat16(t2 * t2);
          } else { // MODE 8: bf16 partial
            ((bf16*)Out)[(long)z * zstride + (long)rr * ldo + c] = __float2bfloat16(v);
          }
        }
      }
    }
  }
}

// Distinct kernel names for clean per-GEMM profile attribution.
__global__ __launch_bounds__(512) void gemm_qkv(
    const bf16* A, const bf16* B, const float* bias, const float* rtab,
    bf16* o1, bf16* o2, bf16* o3)
{
  gemm_body<9, 0>(A, 1024, 0, B, 1024, 0, bias, nullptr, 1024, 0, 0,
                  rtab, o1, o2, o3);
}
__global__ __launch_bounds__(512) void gemm_wo(
    const bf16* A, const bf16* B, bf16* Out)
{
  gemm_body<8, 1>(A, 1024, 256, B, 1024, 256, nullptr, Out, 256, 1024,
                  4194304L, nullptr, nullptr, nullptr, nullptr);
}
__global__ __launch_bounds__(512) void gemm_w1(
    const bf16* A, const bf16* B, const float* bias, bf16* Out)
{
  gemm_body<2, 0>(A, 1024, 0, B, 1024, 0, bias, Out, 1024, 4096, 0,
                  nullptr, nullptr, nullptr, nullptr);
}
__global__ __launch_bounds__(512) void gemm_w2(
    const bf16* A, const bf16* B, bf16* Out)
{
  gemm_body<8, 1>(A, 4096, 1024, B, 4096, 1024, nullptr, Out, 1024, 1024,
                  4194304L, nullptr, nullptr, nullptr, nullptr);
}

// ---------------------------------------------------------------------------
// Split-K(4) reduce of bf16 partials: out = sum_z part[z] + bias + resid(bf16)
// ---------------------------------------------------------------------------
__global__ __launch_bounds__(256) void reduce_k(
    const bf16* __restrict__ part, const float* __restrict__ bias,
    const bf16* __restrict__ resid, float* __restrict__ out)
{
  const int row = blockIdx.x, tid = threadIdx.x;
  const long rb = (long)row * 1024 + tid * 4;
  float a0 = 0, a1 = 0, a2 = 0, a3 = 0;
#pragma unroll
  for (int z = 0; z < 4; ++z) {
    bf16x4s t = *(const bf16x4s*)(part + (long)z * 4194304 + rb);
    a0 += __bfloat162float(t.a); a1 += __bfloat162float(t.b);
    a2 += __bfloat162float(t.c); a3 += __bfloat162float(t.d);
  }
  float4 b = ((const float4*)bias)[tid];
  bf16x4s r = *(const bf16x4s*)(resid + rb);
  float4 o;
  o.x = a0 + b.x + __bfloat162float(r.a);
  o.y = a1 + b.y + __bfloat162float(r.b);
  o.z = a2 + b.z + __bfloat162float(r.c);
  o.w = a3 + b.w + __bfloat162float(r.d);
  *(float4*)(out + rb) = o;
}

// ---------------------------------------------------------------------------
// Fused split-K(4) bf16-partial reduce + residual + LayerNorm. Block per row.
// ---------------------------------------------------------------------------
__global__ __launch_bounds__(256) void reduce_ln(
    const bf16* __restrict__ part, const float* __restrict__ bias,
    const float* __restrict__ resid, const float* __restrict__ g,
    const float* __restrict__ beta, bf16* __restrict__ x2,
    bf16* __restrict__ xn)
{
  const int row = blockIdx.x, tid = threadIdx.x;
  const long rb = (long)row * 1024 + tid * 4;
  float a0 = 0, a1 = 0, a2 = 0, a3 = 0;
#pragma unroll
  for (int z = 0; z < 4; ++z) {
    bf16x4s t = *(const bf16x4s*)(part + (long)z * 4194304 + rb);
    a0 += __bfloat162float(t.a); a1 += __bfloat162float(t.b);
    a2 += __bfloat162float(t.c); a3 += __bfloat162float(t.d);
  }
  float4 bb4 = ((const float4*)bias)[tid];
  float4 rr4 = *(const float4*)(resid + rb);
  float4 v;
  v.x = a0 + bb4.x + rr4.x; v.y = a1 + bb4.y + rr4.y;
  v.z = a2 + bb4.z + rr4.z; v.w = a3 + bb4.w + rr4.w;
  bf16x4s xo;
  xo.a = __float2bfloat16(v.x); xo.b = __float2bfloat16(v.y);
  xo.c = __float2bfloat16(v.z); xo.d = __float2bfloat16(v.w);
  *(bf16x4s*)(x2 + rb) = xo;

  float s = v.x + v.y + v.z + v.w;
  float s2 = v.x * v.x + v.y * v.y + v.z * v.z + v.w * v.w;
#pragma unroll
  for (int o = 32; o; o >>= 1) {
    s += __shfl_down(s, o);
    s2 += __shfl_down(s2, o);
  }
  __shared__ float red[8];
  const int w = tid >> 6, lane = tid & 63;
  if (lane == 0) { red[w] = s; red[4 + w] = s2; }
  __syncthreads();
  float S = red[0] + red[1] + red[2] + red[3];
  float S2 = red[4] + red[5] + red[6] + red[7];
  float mu = S * (1.0f / 1024.0f);
  float rs = rsqrtf(S2 * (1.0f / 1024.0f) - mu * mu + 1e-5f);
  float4 gg = ((const float4*)g)[tid];
  float4 be = ((const float4*)beta)[tid];
  bf16x4s o4;
  o4.a = __float2bfloat16((v.x - mu) * rs * gg.x + be.x);
  o4.b = __float2bfloat16((v.y - mu) * rs * gg.y + be.y);
  o4.c = __float2bfloat16((v.z - mu) * rs * gg.z + be.z);
  o4.d = __float2bfloat16((v.w - mu) * rs * gg.w + be.w);
  *(bf16x4s*)(xn + rb) = o4;
}

// ---------------------------------------------------------------------------
// Fused flash attention + backfill weight conversion.  512 threads/block.
// Blocks [0,512): flash with q-tile 128 (8 waves, 16 q-rows/wave), KV tiles
//   of 64 double-buffered; LDS XOR-swizzled; XCD-pinned (b,h); exp2 domain.
//   KV tile-loads per (b,h): sum(2qt+3) = 24 (vs 44 at q-tile 64).
//   Causal mask applied on the last TWO tiles via global c > r+64 test.
// Blocks [512,5120): convert Wo|W1|W2 fp32->bf16 (2048 elems/block).
// ---------------------------------------------------------------------------
__global__ __launch_bounds__(512) void flash_attn(
    const bf16* __restrict__ qh, const bf16* __restrict__ kh,
    const bf16* __restrict__ vt, bf16* __restrict__ attn,
    const float* __restrict__ cWo, const float* __restrict__ cW1,
    const float* __restrict__ cW2, bf16* __restrict__ wrest)
{
  __shared__ bf16 ks[2][64 * 64];    // K tile  [kv][d]   16 KB
  __shared__ bf16 vs[2][64 * 64];    // V^T tile [d][kv]  16 KB
  __shared__ bf16 pq[128 * 64];      // Q stage, then P   16 KB
  const int tid = threadIdx.x, lane = tid & 63, wv = tid >> 6;
  const int bid = blockIdx.x;

  if (bid >= 512) {                  // ---- weight-conversion backfill ----
    long e = (long)(bid - 512) * 2048 + tid * 4;   // 0..9437183
    const long DD = 1048576, DF = 4194304;
    const float* src; long base;
    if (e < DD)           { src = cWo; base = 0; }
    else if (e < DD + DF) { src = cW1; base = DD; }
    else                  { src = cW2; base = DD + DF; }
    float4 v = *(const float4*)(src + (e - base));
    bf16x4s o4;
    o4.a = __float2bfloat16(v.x);
    o4.b = __float2bfloat16(v.y);
    o4.c = __float2bfloat16(v.z);
    o4.d = __float2bfloat16(v.w);
    *(bf16x4s*)(wrest + e) = o4;
    return;
  }

  const int xcd = bid & 7, sl = bid >> 3;        // sl 0..63
  const int zh = xcd * 16 + (sl >> 2);           // (b,h) pinned to one XCD
  const int qt = sl & 3;                         // q-tile 0..3
  const int b = zh >> 4, h = zh & 15;
  const int q0 = qt * 128;
  const bf16* qb = qh + (long)zh * 32768 + (long)q0 * 64;
  const bf16* kb = kh + (long)zh * 36864;
  const bf16* vb = vt + (long)zh * 36864;

  // stage Q tile (128x64), pre-swizzled source; 2 x 512 chunks of 16B
#pragma unroll
  for (int i = 0; i < 2; ++i) {
    int idx = i * 512 + tid;
    int row = idx >> 3;                // 0..127
    int ce = ((idx & 7) ^ (row & 7)) << 3;
    gload_lds16(qb + (long)row * 64 + ce, pq + idx * 8);
  }
  auto stage_kv = [&](int bb, int j) {
    {   // K tile: 64x64 = 512 chunks, one per thread
      int row = tid >> 3;
      int ce = ((tid & 7) ^ (row & 7)) << 3;
      gload_lds16(kb + (long)(j * 64 + row) * 64 + ce, &ks[bb][tid * 8]);
    }
    {   // V^T tile
      int row = tid >> 3;
      int ce = ((tid & 7) ^ (row & 7)) << 3;
      gload_lds16(vb + (long)row * 576 + j * 64 + ce, &vs[bb][tid * 8]);
    }
  };
  stage_kv(0, 0);
  VMC(0);
  BAR();

  // Q fragments (swizzled read), wave-private rows [wv*16, wv*16+16)
  bf16x8 qf[2];
  {
    int r = wv * 16 + (lane & 15);
#pragma unroll
    for (int kk = 0; kk < 2; ++kk) {
      int c0 = kk * 32 + ((lane >> 4) << 3);
      qf[kk] = *(const bf16x8*)&pq[r * 64 + (c0 ^ ((r & 7) << 3))];
    }
  }

  f32x4 acc_o[4] = {};
  float mrun[4], lrun[4];
#pragma unroll
  for (int jj = 0; jj < 4; ++jj) { mrun[jj] = -1e30f; lrun[jj] = 0.0f; }

  const int nkv = 2 * qt + 3;   // last two tiles partially masked
  int cur = 0;
  for (int j = 0; j < nkv; ++j) {
    if (j + 1 < nkv) stage_kv(cur ^ 1, j + 1);

    // S = Q K^T
    f32x4 sv[4] = {};
    __builtin_amdgcn_s_setprio(1);
#pragma unroll
    for (int kk = 0; kk < 2; ++kk) {
      bf16x8 kf[4];
      int c0 = kk * 32 + ((lane >> 4) << 3);
#pragma unroll
      for (int n = 0; n < 4; ++n) {
        int r = n * 16 + (lane & 15);
        kf[n] = *(const bf16x8*)&ks[cur][r * 64 + (c0 ^ ((r & 7) << 3))];
      }
#pragma unroll
      for (int n = 0; n < 4; ++n) sv[n] = mfma16(qf[kk], kf[n], sv[n]);
    }
    __builtin_amdgcn_s_setprio(0);

    // causal mask on the last two tiles (uniform branch): c > r + 64
    if (j >= nkv - 2) {
#pragma unroll
      for (int n = 0; n < 4; ++n) {
        int c = j * 64 + n * 16 + (lane & 15);       // global col
#pragma unroll
        for (int jj = 0; jj < 4; ++jj) {
          int r = q0 + wv * 16 + ((lane >> 4) << 2) + jj;  // global row
          if (c > r + 64) sv[n][jj] = -1e30f;
        }
      }
    }
    // online softmax (rows owned by 16-lane groups)
#pragma unroll
    for (int jj = 0; jj < 4; ++jj) {
      float pm = fmaxf(fmaxf(sv[0][jj], sv[1][jj]), fmaxf(sv[2][jj], sv[3][jj]));
#pragma unroll
      for (int off = 1; off < 16; off <<= 1) pm = fmaxf(pm, __shfl_xor(pm, off));
      float mnew = fmaxf(mrun[jj], pm);
      float sc = exp2f(mrun[jj] - mnew);
      mrun[jj] = mnew;
      float rs = 0.0f;
#pragma unroll
      for (int n = 0; n < 4; ++n) {
        float p = exp2f(sv[n][jj] - mnew);
        sv[n][jj] = p;
        rs += p;
      }
#pragma unroll
      for (int off = 1; off < 16; off <<= 1) rs += __shfl_xor(rs, off);
      lrun[jj] = lrun[jj] * sc + rs;
#pragma unroll
      for (int nd = 0; nd < 4; ++nd) acc_o[nd][jj] *= sc;
    }
    // P -> bf16 into wave-private LDS rows (swizzled)
#pragma unroll
    for (int n = 0; n < 4; ++n)
#pragma unroll
      for (int jj = 0; jj < 4; ++jj) {
        int pr = wv * 16 + ((lane >> 4) << 2) + jj;
        int pc = n * 16 + (lane & 15);
        pq[pr * 64 + (pc ^ ((pr & 7) << 3))] = __float2bfloat16(sv[n][jj]);
      }
    // O += P * V^T
    __builtin_amdgcn_s_setprio(1);
#pragma unroll
    for (int kk = 0; kk < 2; ++kk) {
      int c0 = kk * 32 + ((lane >> 4) << 3);
      bf16x8 pa, vf[4];
      {
        int r = wv * 16 + (lane & 15);
        pa = *(const bf16x8*)&pq[r * 64 + (c0 ^ ((r & 7) << 3))];
      }
#pragma unroll
      for (int nd = 0; nd < 4; ++nd) {
        int r = nd * 16 + (lane & 15);
        vf[nd] = *(const bf16x8*)&vs[cur][r * 64 + (c0 ^ ((r & 7) << 3))];
      }
#pragma unroll
      for (int nd = 0; nd < 4; ++nd) acc_o[nd] = mfma16(pa, vf[nd], acc_o[nd]);
    }
    __builtin_amdgcn_s_setprio(0);

    if (j + 1 < nkv) {
      LGKM0();
      VMC(0);
      BAR();
      cur ^= 1;
    }
  }
  // epilogue: O / l, scatter into attn (B*T, D) at head column h*64
  bf16* ob = attn + ((long)b * 512 + q0) * 1024 + h * 64;
#pragma unroll
  for (int jj = 0; jj < 4; ++jj) {
    float inv = 1.0f / lrun[jj];
    int r = wv * 16 + ((lane >> 4) << 2) + jj;   // 0..127
#pragma unroll
    for (int nd = 0; nd < 4; ++nd)
      ob[(long)r * 1024 + nd * 16 + (lane & 15)] = __float2bfloat16(acc_o[nd][jj] * inv);
  }
}

// ---------------------------------------------------------------------------
// Merged LN1 + light setup (Wq|Wk|Wv convert, bias concat, rope table).
// ---------------------------------------------------------------------------
__global__ __launch_bounds__(256) void ln_setup(
    const float* __restrict__ xin, const float* __restrict__ mem,
    const float* __restrict__ g, const float* __restrict__ beta,
    bf16* __restrict__ xa,
    const float* __restrict__ wq, const float* __restrict__ wk,
    const float* __restrict__ wv,
    const float* __restrict__ bq, const float* __restrict__ bk,
    const float* __restrict__ bv,
    bf16* __restrict__ wout, float* __restrict__ bout,
    float* __restrict__ tab)
{
  const int blk = blockIdx.x, tid = threadIdx.x;
  if (blk >= 4608) {
    if (blk < 7680) {
      long e = (long)(blk - 4608) * 1024 + tid * 4;
      const long DD = 1048576;
      const float* src; long base;
      if (e < DD)          { src = wq; base = 0; }
      else if (e < 2 * DD) { src = wk; base = DD; }
      else                 { src = wv; base = 2 * DD; }
      float4 v = *(const float4*)(src + (e - base));
      bf16x4s o4;
      o4.a = __float2bfloat16(v.x);
      o4.b = __float2bfloat16(v.y);
      o4.c = __float2bfloat16(v.z);
      o4.d = __float2bfloat16(v.w);
      *(bf16x4s*)(wout + e) = o4;
    } else if (blk < 7692) {
      int i = (blk - 7680) * 256 + tid;
      if (i < 1024)      bout[i] = bq[i];
      else if (i < 2048) bout[i] = bk[i - 1024];
      else if (i < 3072) bout[i] = bv[i - 2048];
    } else {
      int i = (blk - 7692) * 256 + tid;
      if (i < 9216) {
        int p = i >> 4, f = i & 15;
        float invf = expf(-(float)f * 0.5756462732485114f);
        float ang = (float)p * invf;
        tab[i] = cosf(ang);
        tab[9216 + i] = sinf(ang);
      }
    }
    return;
  }
  const int row = blk;
  int b = row / 576, p = row % 576;
  const float* src = (p < 64) ? (mem + ((long)b * 64 + p) * 1024)
                              : (xin + ((long)b * 512 + (p - 64)) * 1024);
  float4 v = ((const float4*)src)[tid];
  float s = v.x + v.y + v.z + v.w;
  float s2 = v.x * v.x + v.y * v.y + v.z * v.z + v.w * v.w;
#pragma unroll
  for (int o = 32; o; o >>= 1) {
    s += __shfl_down(s, o);
    s2 += __shfl_down(s2, o);
  }
  __shared__ float red[8];
  const int w = tid >> 6, lane = tid & 63;
  if (lane == 0) { red[w] = s; red[4 + w] = s2; }
  __syncthreads();
  float S = red[0] + red[1] + red[2] + red[3];
  float S2 = red[4] + red[5] + red[6] + red[7];
  float mu = S * (1.0f / 1024.0f);
  float rs = rsqrtf(S2 * (1.0f / 1024.0f) - mu * mu + 1e-5f);
  float4 gg = ((const float4*)g)[tid];
  float4 bb = ((const float4*)beta)[tid];
  bf16x4s o4;
  o4.a = __float2bfloat16((v.x - mu) * rs * gg.x + bb.x);
  o4.b = __float2bfloat16((v.y - mu) * rs * gg.y + bb.y);
  o4.c = __float2bfloat16((v.z - mu) * rs * gg.z + bb.z);
  o4.d = __float2bfloat16((v.w - mu) * rs * gg.w + bb.w);
  *(bf16x4s*)(xa + (long)row * 1024 + tid * 4) = o4;
}

// ---------------------------------------------------------------------------
extern "C" void kernel_launch(void* const* d_in, const int* in_sizes, int n_in,
                              void* d_out, int out_size, void* d_ws, size_t ws_size,
                              hipStream_t stream)
{
  (void)in_sizes; (void)n_in; (void)out_size; (void)ws_size;
  const float* x    = (const float*)d_in[0];
  const float* mem  = (const float*)d_in[1];
  const float* Wq   = (const float*)d_in[2];
  const float* bq   = (const float*)d_in[3];
  const float* Wk   = (const float*)d_in[4];
  const float* bk   = (const float*)d_in[5];
  const float* Wv   = (const float*)d_in[6];
  const float* bv   = (const float*)d_in[7];
  const float* Wo   = (const float*)d_in[8];
  const float* bo   = (const float*)d_in[9];
  const float* W1   = (const float*)d_in[10];
  const float* b1   = (const float*)d_in[11];
  const float* W2   = (const float*)d_in[12];
  const float* b2   = (const float*)d_in[13];
  const float* g_a  = (const float*)d_in[14];
  const float* bt_a = (const float*)d_in[15];
  const float* g_m  = (const float*)d_in[16];
  const float* bt_m = (const float*)d_in[17];
  float* out = (float*)d_out;

  char* ws = (char*)d_ws;
  size_t off = 0;
  auto carve = [&](size_t bytes) -> void* {
    void* p = ws + off;
    off = (off + bytes + 255) & ~(size_t)255;
    return p;
  };
  bf16*  wB    = (bf16*)carve(12582912L * 2);        // packed bf16 weights
  float* bqkv  = (float*)carve(3072 * 4);
  float* rtab  = (float*)carve(9216 * 2 * 4);        // rope cos/sin table
  bf16*  xa    = (bf16*)carve(4608L * 1024 * 2);     // LN1 out
  bf16*  qh    = (bf16*)carve(8L * 16 * 512 * 64 * 2);
  bf16*  kh    = (bf16*)carve(8L * 16 * 576 * 64 * 2);
  bf16*  vt    = (bf16*)carve(8L * 16 * 576 * 64 * 2);
  bf16*  attn  = (bf16*)carve(4096L * 1024 * 2);     // flash out, (B*T, D)
  bf16*  x2    = (bf16*)carve(4096L * 1024 * 2);     // post-attn residual bf16
  bf16*  xn    = (bf16*)carve(4096L * 1024 * 2);     // LN2 out
  bf16*  hbuf  = (bf16*)carve(4096L * 4096 * 2);     // relu^2 hidden
  bf16*  partsb= (bf16*)carve(4L * 4096 * 1024 * 2); // split-K bf16 partials

  // LN1 + {Wq,Wk,Wv convert, bias concat, rope table}
  ln_setup<<<7728, 256, 0, stream>>>(x, mem, g_a, bt_a, xa,
                                     Wq, Wk, Wv, bq, bk, bv, wB, bqkv, rtab);

  // QKV fused (bias+RoPE+reshape+Q-scale, V transposed): grid (12,18)
  gemm_qkv<<<dim3(12, 18, 1), 512, 0, stream>>>(xa, wB, bqkv, rtab, qh, kh, vt);

  // flash attention (512 blocks, q-tile 128) + Wo/W1/W2 conversion backfill
  flash_attn<<<5120, 512, 0, stream>>>(qh, kh, vt, attn,
                                       Wo, W1, W2, wB + 3145728L);

  // Wo split-K=4 (bf16 partials): (4096,1024)x(1024,1024)^T, slice K=256
  gemm_wo<<<dim3(4, 16, 4), 512, 0, stream>>>(attn, wB + 3145728L, partsb);
  // fused: x2(bf16) = sum(parts)+bo+x ; xn = LN
  reduce_ln<<<4096, 256, 0, stream>>>(partsb, bo, x, g_m, bt_m, x2, xn);

  // W1 + relu^2: (4096,1024)x(4096,1024)^T -> (4096,4096) bf16, grid (16,16)
  gemm_w1<<<dim3(16, 16, 1), 512, 0, stream>>>(xn, wB + 4194304L, b1, hbuf);

  // W2 split-K=4 (bf16 partials): (4096,4096)x(1024,4096)^T, slice K=1024
  gemm_w2<<<dim3(4, 16, 4), 512, 0, stream>>>(hbuf, wB + 8388608L, partsb);
  reduce_k<<<4096, 256, 0, stream>>>(partsb, b2, x2, out);
}

// Round 17
// 195.941 us; speedup vs baseline: 1.0118x; 1.0118x over previous
//
#include <hip/hip_runtime.h>
#include <hip/hip_bf16.h>
#include <cmath>

// Problem constants: B=8 T=512 M=64 D=1024 H=16 DFF=4096, DH=64, ROT=32, L=576
using bf16 = __hip_bfloat16;
typedef __attribute__((ext_vector_type(8))) __bf16 bf16x8;
typedef __attribute__((ext_vector_type(4))) float f32x4;

struct __align__(8) bf16x4s { bf16 a, b, c, d; };

__device__ inline void gload_lds16(const void* g, void* l) {
  __builtin_amdgcn_global_load_lds(
      (__attribute__((address_space(1))) void*)g,
      (__attribute__((address_space(3))) void*)l, 16, 0, 0);
}

__device__ inline f32x4 mfma16(bf16x8 a, bf16x8 b, f32x4 c) {
  return __builtin_amdgcn_mfma_f32_16x16x32_bf16(a, b, c, 0, 0, 0);
}

#define BAR() __builtin_amdgcn_s_barrier()
#define VMC(N) asm volatile("s_waitcnt vmcnt(" #N ")" ::: "memory")
#define LGKM0() asm volatile("s_waitcnt lgkmcnt(0)" ::: "memory")

// ---------------------------------------------------------------------------
// Common GEMM body: C = A * B^T, 256x256 tile, BK=64, 512 threads (8 waves,
// 2x4; per-wave 128x64 output). 8-phase schedule (16-MFMA quadrants),
// counted vmcnt(4) at phases 4/8 only — round-10/13 proven best.
// LDS: 8 half-slots x 16KB (2-tile ring). XOR swizzle byte^=((row&7)<<4):
// linear gload_lds dest + pre-swizzled global source; ds_reads same XOR.
// CHUNK 0: XCD regions (gx/4 x gy/2); CHUNK 1: XCD owns bx rows (split-K).
// MODE 2: bf16 out = relu(acc+bias)^2      (direct stores)
// MODE 8: bf16 partial: Out[z*zstride+r*ldo+c]  (direct stores)
// MODE 9: fused QKV: bias+RoPE+reshape+Q-scale via per-wave LDS transpose;
//         V is written TRANSPOSED directly into vt[zh][d][p] (o3).
// ---------------------------------------------------------------------------
template<int MODE, int CHUNK>
__device__ __forceinline__ void gemm_body(
    const bf16* __restrict__ A, int lda, long sA,
    const bf16* __restrict__ B, int ldb, long sB,
    const float* __restrict__ bias,
    void* __restrict__ Out,
    int K, int ldo, long zstride,
    const float* __restrict__ rtab,
    bf16* __restrict__ o1, bf16* __restrict__ o2, bf16* __restrict__ o3)
{
  __shared__ bf16 lds[65536];   // 128 KiB
  const int tid = threadIdx.x, lane = tid & 63, wid = tid >> 6;
  const int wr = wid >> 2, wc = wid & 3;       // 2x4 wave grid
  const int gx = gridDim.x;
  const int bidl = blockIdx.x + gx * blockIdx.y;
  const int xcd = bidl & 7, slot_ = bidl >> 3;
  int bx, by;
  if constexpr (CHUNK == 0) {
    const int sx = gx >> 2, sy = gridDim.y >> 1;
    bx = (xcd & 3) * sx + slot_ % sx;
    by = (xcd >> 2) * sy + slot_ / sx;
  } else {
    bx = slot_ % gx;
    by = xcd * (gridDim.y >> 3) + slot_ / gx;
  }
  const int m0 = by * 256, n0 = bx * 256;
  const int z = blockIdx.z;
  const bf16* Ab = A + (long)z * sA;
  const bf16* Bb = B + (long)z * sB;
  const int nt = K >> 6;        // even, >= 2

  f32x4 acc[8][4] = {};

  auto STAGE = [&](int par, int t, int part) {
    const bf16* src = (part < 2) ? Ab : Bb;
    const int ld = (part < 2) ? lda : ldb;
    const int rb = ((part < 2) ? m0 : n0) + (part & 1) * 128;
    const int k0 = t << 6;
    bf16* dst = &lds[(par * 4 + part) * 8192];
#pragma unroll
    for (int j = 0; j < 2; ++j) {
      int idx = j * 512 + tid;            // 0..1023 chunk of 16B
      int row = idx >> 3;                 // 0..127
      int ce = ((idx & 7) ^ (row & 7)) << 3;  // pre-swizzled source column
      gload_lds16(src + (long)(rb + row) * ld + k0 + ce, dst + idx * 8);
    }
  };
  auto load_a = [&](bf16x8 (&a_)[4][2], int par, int mh) {
#pragma unroll
    for (int mf = 0; mf < 4; ++mf)
#pragma unroll
      for (int kk = 0; kk < 2; ++kk) {
        int r = mh * 64 + mf * 16 + (lane & 15);
        int cb = (kk * 64 + ((lane >> 4) << 4)) ^ ((r & 7) << 4);
        a_[mf][kk] = *(const bf16x8*)&lds[(par * 4 + wr) * 8192 + r * 64 + (cb >> 1)];
      }
  };
  auto load_b = [&](bf16x8 (&b_)[2][2], int par, int nh) {
#pragma unroll
    for (int nf = 0; nf < 2; ++nf)
#pragma unroll
      for (int kk = 0; kk < 2; ++kk) {
        int r = (wc & 1) * 64 + (nh * 2 + nf) * 16 + (lane & 15);
        int cb = (kk * 64 + ((lane >> 4) << 4)) ^ ((r & 7) << 4);
        b_[nf][kk] = *(const bf16x8*)&lds[(par * 4 + 2 + (wc >> 1)) * 8192 + r * 64 + (cb >> 1)];
      }
  };
  // kk OUTERMOST: 8 independent MFMAs per kk (no back-to-back same-acc deps)
  auto qmfma = [&](bf16x8 (&a_)[4][2], bf16x8 (&b_)[2][2], int mh, int nh) {
    __builtin_amdgcn_s_setprio(1);
#pragma unroll
    for (int kk = 0; kk < 2; ++kk)
#pragma unroll
      for (int mf = 0; mf < 4; ++mf)
#pragma unroll
        for (int nf = 0; nf < 2; ++nf)
          acc[mh * 4 + mf][nh * 2 + nf] =
              mfma16(a_[mf][kk], b_[nf][kk], acc[mh * 4 + mf][nh * 2 + nf]);
    __builtin_amdgcn_s_setprio(0);
  };

  // prologue: tile0 {A0,A1,B0,B1}, then 1.B0, 1.A0 (stay in flight)
  STAGE(0, 0, 0); STAGE(0, 0, 1); STAGE(0, 0, 2); STAGE(0, 0, 3);
  STAGE(1, 1, 2); STAGE(1, 1, 0);
  VMC(4);
  BAR();

  const int half = nt >> 1;
  for (int i = 0; i < half; ++i) {
    const int u = 2 * i;
    const bool full = (i < half - 1);
    bf16x8 a[4][2], b0[2][2], b1[2][2];
    // ======== tile u (parity 0) ========
    load_a(a, 0, 0); load_b(b0, 0, 0);
    STAGE(1, u + 1, 3);
    BAR();
    qmfma(a, b0, 0, 0);
    BAR();
    load_b(b1, 0, 1);
    STAGE(1, u + 1, 1);
    BAR();
    qmfma(a, b1, 0, 1);
    BAR();
    load_a(a, 0, 1);
    if (full) STAGE(0, u + 2, 2);
    BAR();
    qmfma(a, b1, 1, 1);
    BAR();
    if (full) STAGE(0, u + 2, 0);
    BAR();
    qmfma(a, b0, 1, 0);
    if (full) { VMC(4); } else { VMC(0); }
    BAR();
    // ======== tile u+1 (parity 1) ========
    load_a(a, 1, 0); load_b(b0, 1, 0);
    if (full) STAGE(0, u + 2, 3);
    BAR();
    qmfma(a, b0, 0, 0);
    BAR();
    load_b(b1, 1, 1);
    if (full) STAGE(0, u + 2, 1);
    BAR();
    qmfma(a, b1, 0, 1);
    BAR();
    load_a(a, 1, 1);
    if (full) STAGE(1, u + 3, 2);
    BAR();
    qmfma(a, b1, 1, 1);
    BAR();
    if (full) STAGE(1, u + 3, 0);
    BAR();
    qmfma(a, b0, 1, 0);
    if (full) VMC(4);
    BAR();
  }

  // epilogue: C/D layout col=lane&15, row=(lane>>4)*4+j  [HW-verified m89/m91]
  const int cb0 = n0 + wc * 64 + (lane & 15);
  const int rb0 = m0 + wr * 128 + ((lane >> 4) << 2);

  if constexpr (MODE == 9) {
    // fused QKV via per-wave LDS transpose (slot is free after final BAR)
    bf16* slot = &lds[wid * 8192];
    const int l15 = lane & 15;
    const int matq = n0 >> 10;               // 0=Q 1=K 2=V
    const int hh = ((n0 & 1023) >> 6) + wc;  // head index
    const float b0v = bias[n0 + wc * 64 + l15];
    const float b1v = bias[n0 + wc * 64 + l15 + 16];
    const float b2v = bias[n0 + wc * 64 + l15 + 32];
    const float b3v = bias[n0 + wc * 64 + l15 + 48];
#pragma unroll
    for (int mf = 0; mf < 8; ++mf) {
#pragma unroll
      for (int j = 0; j < 4; ++j) {
        int lr = mf * 16 + ((lane >> 4) << 2) + j;   // local row 0..127
        float a0 = acc[mf][0][j] + b0v;
        float a1 = acc[mf][1][j] + b1v;
        float a2 = acc[mf][2][j] + b2v;
        float a3 = acc[mf][3][j] + b3v;
        if (matq < 2) {
          int rr = m0 + wr * 128 + lr;
          int p = rr % 576;
          float cs = rtab[p * 16 + l15];
          float sn = rtab[9216 + p * 16 + l15];
          float r0 = a0 * cs - a1 * sn;
          float r1 = a1 * cs + a0 * sn;
          a0 = r0; a1 = r1;
          if (matq == 0) {
            const float QS = 0.18033688011112043f;  // 0.125 * log2(e)
            a0 *= QS; a1 *= QS; a2 *= QS; a3 *= QS;
          }
        }
        int sw = (lr & 7) << 3;
        slot[lr * 64 + ((l15) ^ sw)]      = __float2bfloat16(a0);
        slot[lr * 64 + ((l15 + 16) ^ sw)] = __float2bfloat16(a1);
        slot[lr * 64 + ((l15 + 32) ^ sw)] = __float2bfloat16(a2);
        slot[lr * 64 + ((l15 + 48) ^ sw)] = __float2bfloat16(a3);
      }
    }
    __syncthreads();
    if (matq == 2) {
      // V: write TRANSPOSED into vt[zh][d][p]; d = lane, 8-p runs.
#pragma unroll
      for (int it = 0; it < 16; ++it) {
        int pr0 = it * 8;
        bf16 tmp[8] __attribute__((aligned(16)));
#pragma unroll
        for (int j = 0; j < 8; ++j)
          tmp[j] = slot[(pr0 + j) * 64 + (lane ^ ((j & 7) << 3))];
        int rr = m0 + wr * 128 + pr0;
        int b_ = rr / 576, p = rr - b_ * 576;
        int zh = b_ * 16 + hh;
        *(bf16x8*)(o3 + (long)zh * 36864 + (long)lane * 576 + p) =
            *(const bf16x8*)tmp;
      }
    } else {
#pragma unroll
      for (int it = 0; it < 16; ++it) {
        int u = it * 64 + lane;
        int r_s = u >> 3, c_s = u & 7;          // row 0..127, 8-col chunk
        int rr = m0 + wr * 128 + r_s;
        bf16x8 val = *(const bf16x8*)&slot[r_s * 64 + ((c_s ^ (r_s & 7)) << 3)];
        int b_ = rr / 576, p = rr - b_ * 576;
        int zh = b_ * 16 + hh;
        if (matq == 0) {
          if (p >= 64)
            *(bf16x8*)(o1 + ((long)zh * 512 + (p - 64)) * 64 + c_s * 8) = val;
        } else {
          *(bf16x8*)(o2 + ((long)zh * 576 + p) * 64 + c_s * 8) = val;
        }
      }
    }
  } else {
    // direct stores (round-7/10 proven form)
#pragma unroll
    for (int mf = 0; mf < 8; ++mf) {
#pragma unroll
      for (int nf = 0; nf < 4; ++nf) {
        int c = cb0 + nf * 16;
#pragma unroll
        for (int j = 0; j < 4; ++j) {
          int rr = rb0 + mf * 16 + j;
          float v = acc[mf][nf][j];
          if constexpr (MODE == 2) {
            float t2 = fmaxf(v + bias[c], 0.0f);
            ((bf16*)Out)[(long)rr * ldo + c] = __float2bfloat16(t2 * t2);
          } else { // MODE 8: bf16 partial
            ((bf16*)Out)[(long)z * zstride + (long)rr * ldo + c] = __float2bfloat16(v);
          }
        }
      }
    }
  }
}

// Distinct kernel names for clean per-GEMM profile attribution.
__global__ __launch_bounds__(512) void gemm_qkv(
    const bf16* A, const bf16* B, const float* bias, const float* rtab,
    bf16* o1, bf16* o2, bf16* o3)
{
  gemm_body<9, 0>(A, 1024, 0, B, 1024, 0, bias, nullptr, 1024, 0, 0,
                  rtab, o1, o2, o3);
}
__global__ __launch_bounds__(512) void gemm_wo(
    const bf16* A, const bf16* B, bf16* Out)
{
  gemm_body<8, 1>(A, 1024, 256, B, 1024, 256, nullptr, Out, 256, 1024,
                  4194304L, nullptr, nullptr, nullptr, nullptr);
}
__global__ __launch_bounds__(512) void gemm_w1(
    const bf16* A, const bf16* B, const float* bias, bf16* Out)
{
  gemm_body<2, 0>(A, 1024, 0, B, 1024, 0, bias, Out, 1024, 4096, 0,
                  nullptr, nullptr, nullptr, nullptr);
}
__global__ __launch_bounds__(512) void gemm_w2(
    const bf16* A, const bf16* B, bf16* Out)
{
  gemm_body<8, 1>(A, 4096, 1024, B, 4096, 1024, nullptr, Out, 1024, 1024,
                  4194304L, nullptr, nullptr, nullptr, nullptr);
}

// ---------------------------------------------------------------------------
// Split-K(4) reduce of bf16 partials: out = sum_z part[z] + bias + resid(bf16)
// ---------------------------------------------------------------------------
__global__ __launch_bounds__(256) void reduce_k(
    const bf16* __restrict__ part, const float* __restrict__ bias,
    const bf16* __restrict__ resid, float* __restrict__ out)
{
  const int row = blockIdx.x, tid = threadIdx.x;
  const long rb = (long)row * 1024 + tid * 4;
  float a0 = 0, a1 = 0, a2 = 0, a3 = 0;
#pragma unroll
  for (int z = 0; z < 4; ++z) {
    bf16x4s t = *(const bf16x4s*)(part + (long)z * 4194304 + rb);
    a0 += __bfloat162float(t.a); a1 += __bfloat162float(t.b);
    a2 += __bfloat162float(t.c); a3 += __bfloat162float(t.d);
  }
  float4 b = ((const float4*)bias)[tid];
  bf16x4s r = *(const bf16x4s*)(resid + rb);
  float4 o;
  o.x = a0 + b.x + __bfloat162float(r.a);
  o.y = a1 + b.y + __bfloat162float(r.b);
  o.z = a2 + b.z + __bfloat162float(r.c);
  o.w = a3 + b.w + __bfloat162float(r.d);
  *(float4*)(out + rb) = o;
}

// ---------------------------------------------------------------------------
// Fused split-K(4) bf16-partial reduce + residual + LayerNorm. Block per row.
// ---------------------------------------------------------------------------
__global__ __launch_bounds__(256) void reduce_ln(
    const bf16* __restrict__ part, const float* __restrict__ bias,
    const float* __restrict__ resid, const float* __restrict__ g,
    const float* __restrict__ beta, bf16* __restrict__ x2,
    bf16* __restrict__ xn)
{
  const int row = blockIdx.x, tid = threadIdx.x;
  const long rb = (long)row * 1024 + tid * 4;
  float a0 = 0, a1 = 0, a2 = 0, a3 = 0;
#pragma unroll
  for (int z = 0; z < 4; ++z) {
    bf16x4s t = *(const bf16x4s*)(part + (long)z * 4194304 + rb);
    a0 += __bfloat162float(t.a); a1 += __bfloat162float(t.b);
    a2 += __bfloat162float(t.c); a3 += __bfloat162float(t.d);
  }
  float4 bb4 = ((const float4*)bias)[tid];
  float4 rr4 = *(const float4*)(resid + rb);
  float4 v;
  v.x = a0 + bb4.x + rr4.x; v.y = a1 + bb4.y + rr4.y;
  v.z = a2 + bb4.z + rr4.z; v.w = a3 + bb4.w + rr4.w;
  bf16x4s xo;
  xo.a = __float2bfloat16(v.x); xo.b = __float2bfloat16(v.y);
  xo.c = __float2bfloat16(v.z); xo.d = __float2bfloat16(v.w);
  *(bf16x4s*)(x2 + rb) = xo;

  float s = v.x + v.y + v.z + v.w;
  float s2 = v.x * v.x + v.y * v.y + v.z * v.z + v.w * v.w;
#pragma unroll
  for (int o = 32; o; o >>= 1) {
    s += __shfl_down(s, o);
    s2 += __shfl_down(s2, o);
  }
  __shared__ float red[8];
  const int w = tid >> 6, lane = tid & 63;
  if (lane == 0) { red[w] = s; red[4 + w] = s2; }
  __syncthreads();
  float S = red[0] + red[1] + red[2] + red[3];
  float S2 = red[4] + red[5] + red[6] + red[7];
  float mu = S * (1.0f / 1024.0f);
  float rs = rsqrtf(S2 * (1.0f / 1024.0f) - mu * mu + 1e-5f);
  float4 gg = ((const float4*)g)[tid];
  float4 be = ((const float4*)beta)[tid];
  bf16x4s o4;
  o4.a = __float2bfloat16((v.x - mu) * rs * gg.x + be.x);
  o4.b = __float2bfloat16((v.y - mu) * rs * gg.y + be.y);
  o4.c = __float2bfloat16((v.z - mu) * rs * gg.z + be.z);
  o4.d = __float2bfloat16((v.w - mu) * rs * gg.w + be.w);
  *(bf16x4s*)(xn + rb) = o4;
}

// ---------------------------------------------------------------------------
// Fused flash attention + backfill weight conversion.
// Blocks [0,1024): flash (q-tile 64, 4 waves, KV tiles 64, double-buffered,
//   LDS XOR-swizzled, XCD-pinned (b,h), softmax in exp2 domain).
// Blocks [1024,10240): convert Wo|W1|W2 fp32->bf16 (1024 elems/block).
// ---------------------------------------------------------------------------
__global__ __launch_bounds__(256) void flash_attn(
    const bf16* __restrict__ qh, const bf16* __restrict__ kh,
    const bf16* __restrict__ vt, bf16* __restrict__ attn,
    const float* __restrict__ cWo, const float* __restrict__ cW1,
    const float* __restrict__ cW2, bf16* __restrict__ wrest)
{
  __shared__ bf16 ks[2][64 * 64];
  __shared__ bf16 vs[2][64 * 64];
  __shared__ bf16 pq[64 * 64];
  const int tid = threadIdx.x, lane = tid & 63, wv = tid >> 6;
  const int bid = blockIdx.x;

  if (bid >= 1024) {                 // ---- weight-conversion backfill ----
    long e = (long)(bid - 1024) * 1024 + tid * 4;
    const long DD = 1048576, DF = 4194304;
    const float* src; long base;
    if (e < DD)           { src = cWo; base = 0; }
    else if (e < DD + DF) { src = cW1; base = DD; }
    else                  { src = cW2; base = DD + DF; }
    float4 v = *(const float4*)(src + (e - base));
    bf16x4s o4;
    o4.a = __float2bfloat16(v.x);
    o4.b = __float2bfloat16(v.y);
    o4.c = __float2bfloat16(v.z);
    o4.d = __float2bfloat16(v.w);
    *(bf16x4s*)(wrest + e) = o4;
    return;
  }

  const int xcd = bid & 7, sl = bid >> 3;
  const int zh = xcd * 16 + (sl >> 3);   // (b,h) group pinned to one XCD
  const int qt = sl & 7;
  const int b = zh >> 4, h = zh & 15;
  const int q0 = qt * 64;
  const bf16* qb = qh + (long)zh * 32768 + (long)q0 * 64;
  const bf16* kb = kh + (long)zh * 36864;
  const bf16* vb = vt + (long)zh * 36864;

#pragma unroll
  for (int i = 0; i < 2; ++i) {
    int idx = i * 256 + tid;
    int row = idx >> 3;
    int ce = ((idx & 7) ^ (row & 7)) << 3;
    gload_lds16(qb + (long)row * 64 + ce, pq + idx * 8);
  }
  auto stage_kv = [&](int bb, int j) {
#pragma unroll
    for (int it = 0; it < 2; ++it) {
      int idx = it * 256 + tid;
      int row = idx >> 3;
      int ce = ((idx & 7) ^ (row & 7)) << 3;
      gload_lds16(kb + (long)(j * 64 + row) * 64 + ce, &ks[bb][idx * 8]);
    }
#pragma unroll
    for (int it = 0; it < 2; ++it) {
      int idx = it * 256 + tid;
      int row = idx >> 3;
      int ce = ((idx & 7) ^ (row & 7)) << 3;
      gload_lds16(vb + (long)row * 576 + j * 64 + ce, &vs[bb][idx * 8]);
    }
  };
  stage_kv(0, 0);
  VMC(0);
  BAR();

  bf16x8 qf[2];
  {
    int r = wv * 16 + (lane & 15);
#pragma unroll
    for (int kk = 0; kk < 2; ++kk) {
      int c0 = kk * 32 + ((lane >> 4) << 3);
      qf[kk] = *(const bf16x8*)&pq[r * 64 + (c0 ^ ((r & 7) << 3))];
    }
  }

  f32x4 acc_o[4] = {};
  float mrun[4], lrun[4];
#pragma unroll
  for (int jj = 0; jj < 4; ++jj) { mrun[jj] = -1e30f; lrun[jj] = 0.0f; }

  const int nkv = qt + 2;
  int cur = 0;
  for (int j = 0; j < nkv; ++j) {
    if (j + 1 < nkv) stage_kv(cur ^ 1, j + 1);

    f32x4 sv[4] = {};
    __builtin_amdgcn_s_setprio(1);
#pragma unroll
    for (int kk = 0; kk < 2; ++kk) {
      bf16x8 kf[4];
      int c0 = kk * 32 + ((lane >> 4) << 3);
#pragma unroll
      for (int n = 0; n < 4; ++n) {
        int r = n * 16 + (lane & 15);
        kf[n] = *(const bf16x8*)&ks[cur][r * 64 + (c0 ^ ((r & 7) << 3))];
      }
#pragma unroll
      for (int n = 0; n < 4; ++n) sv[n] = mfma16(qf[kk], kf[n], sv[n]);
    }
    __builtin_amdgcn_s_setprio(0);

    if (j == nkv - 1) {
#pragma unroll
      for (int n = 0; n < 4; ++n) {
        int c = n * 16 + (lane & 15);
#pragma unroll
        for (int jj = 0; jj < 4; ++jj) {
          int r = wv * 16 + ((lane >> 4) << 2) + jj;
          if (c > r) sv[n][jj] = -1e30f;
        }
      }
    }
#pragma unroll
    for (int jj = 0; jj < 4; ++jj) {
      float pm = fmaxf(fmaxf(sv[0][jj], sv[1][jj]), fmaxf(sv[2][jj], sv[3][jj]));
#pragma unroll
      for (int off = 1; off < 16; off <<= 1) pm = fmaxf(pm, __shfl_xor(pm, off));
      float mnew = fmaxf(mrun[jj], pm);
      float sc = exp2f(mrun[jj] - mnew);
      mrun[jj] = mnew;
      float rs = 0.0f;
#pragma unroll
      for (int n = 0; n < 4; ++n) {
        float p = exp2f(sv[n][jj] - mnew);
        sv[n][jj] = p;
        rs += p;
      }
#pragma unroll
      for (int off = 1; off < 16; off <<= 1) rs += __shfl_xor(rs, off);
      lrun[jj] = lrun[jj] * sc + rs;
#pragma unroll
      for (int nd = 0; nd < 4; ++nd) acc_o[nd][jj] *= sc;
    }
#pragma unroll
    for (int n = 0; n < 4; ++n)
#pragma unroll
      for (int jj = 0; jj < 4; ++jj) {
        int pr = wv * 16 + ((lane >> 4) << 2) + jj;
        int pc = n * 16 + (lane & 15);
        pq[pr * 64 + (pc ^ ((pr & 7) << 3))] = __float2bfloat16(sv[n][jj]);
      }
    __builtin_amdgcn_s_setprio(1);
#pragma unroll
    for (int kk = 0; kk < 2; ++kk) {
      int c0 = kk * 32 + ((lane >> 4) << 3);
      bf16x8 pa, vf[4];
      {
        int r = wv * 16 + (lane & 15);
        pa = *(const bf16x8*)&pq[r * 64 + (c0 ^ ((r & 7) << 3))];
      }
#pragma unroll
      for (int nd = 0; nd < 4; ++nd) {
        int r = nd * 16 + (lane & 15);
        vf[nd] = *(const bf16x8*)&vs[cur][r * 64 + (c0 ^ ((r & 7) << 3))];
      }
#pragma unroll
      for (int nd = 0; nd < 4; ++nd) acc_o[nd] = mfma16(pa, vf[nd], acc_o[nd]);
    }
    __builtin_amdgcn_s_setprio(0);

    if (j + 1 < nkv) {
      LGKM0();
      VMC(0);
      BAR();
      cur ^= 1;
    }
  }
  bf16* ob = attn + ((long)b * 512 + q0) * 1024 + h * 64;
#pragma unroll
  for (int jj = 0; jj < 4; ++jj) {
    float inv = 1.0f / lrun[jj];
    int r = wv * 16 + ((lane >> 4) << 2) + jj;
#pragma unroll
    for (int nd = 0; nd < 4; ++nd)
      ob[(long)r * 1024 + nd * 16 + (lane & 15)] = __float2bfloat16(acc_o[nd][jj] * inv);
  }
}

// ---------------------------------------------------------------------------
// Merged LN1 + light setup (Wq|Wk|Wv convert, bias concat, rope table).
// ---------------------------------------------------------------------------
__global__ __launch_bounds__(256) void ln_setup(
    const float* __restrict__ xin, const float* __restrict__ mem,
    const float* __restrict__ g, const float* __restrict__ beta,
    bf16* __restrict__ xa,
    const float* __restrict__ wq, const float* __restrict__ wk,
    const float* __restrict__ wv,
    const float* __restrict__ bq, const float* __restrict__ bk,
    const float* __restrict__ bv,
    bf16* __restrict__ wout, float* __restrict__ bout,
    float* __restrict__ tab)
{
  const int blk = blockIdx.x, tid = threadIdx.x;
  if (blk >= 4608) {
    if (blk < 7680) {
      long e = (long)(blk - 4608) * 1024 + tid * 4;
      const long DD = 1048576;
      const float* src; long base;
      if (e < DD)          { src = wq; base = 0; }
      else if (e < 2 * DD) { src = wk; base = DD; }
      else                 { src = wv; base = 2 * DD; }
      float4 v = *(const float4*)(src + (e - base));
      bf16x4s o4;
      o4.a = __float2bfloat16(v.x);
      o4.b = __float2bfloat16(v.y);
      o4.c = __float2bfloat16(v.z);
      o4.d = __float2bfloat16(v.w);
      *(bf16x4s*)(wout + e) = o4;
    } else if (blk < 7692) {
      int i = (blk - 7680) * 256 + tid;
      if (i < 1024)      bout[i] = bq[i];
      else if (i < 2048) bout[i] = bk[i - 1024];
      else if (i < 3072) bout[i] = bv[i - 2048];
    } else {
      int i = (blk - 7692) * 256 + tid;
      if (i < 9216) {
        int p = i >> 4, f = i & 15;
        float invf = expf(-(float)f * 0.5756462732485114f);
        float ang = (float)p * invf;
        tab[i] = cosf(ang);
        tab[9216 + i] = sinf(ang);
      }
    }
    return;
  }
  const int row = blk;
  int b = row / 576, p = row % 576;
  const float* src = (p < 64) ? (mem + ((long)b * 64 + p) * 1024)
                              : (xin + ((long)b * 512 + (p - 64)) * 1024);
  float4 v = ((const float4*)src)[tid];
  float s = v.x + v.y + v.z + v.w;
  float s2 = v.x * v.x + v.y * v.y + v.z * v.z + v.w * v.w;
#pragma unroll
  for (int o = 32; o; o >>= 1) {
    s += __shfl_down(s, o);
    s2 += __shfl_down(s2, o);
  }
  __shared__ float red[8];
  const int w = tid >> 6, lane = tid & 63;
  if (lane == 0) { red[w] = s; red[4 + w] = s2; }
  __syncthreads();
  float S = red[0] + red[1] + red[2] + red[3];
  float S2 = red[4] + red[5] + red[6] + red[7];
  float mu = S * (1.0f / 1024.0f);
  float rs = rsqrtf(S2 * (1.0f / 1024.0f) - mu * mu + 1e-5f);
  float4 gg = ((const float4*)g)[tid];
  float4 bb = ((const float4*)beta)[tid];
  bf16x4s o4;
  o4.a = __float2bfloat16((v.x - mu) * rs * gg.x + bb.x);
  o4.b = __float2bfloat16((v.y - mu) * rs * gg.y + bb.y);
  o4.c = __float2bfloat16((v.z - mu) * rs * gg.z + bb.z);
  o4.d = __float2bfloat16((v.w - mu) * rs * gg.w + bb.w);
  *(bf16x4s*)(xa + (long)row * 1024 + tid * 4) = o4;
}

// ---------------------------------------------------------------------------
extern "C" void kernel_launch(void* const* d_in, const int* in_sizes, int n_in,
                              void* d_out, int out_size, void* d_ws, size_t ws_size,
                              hipStream_t stream)
{
  (void)in_sizes; (void)n_in; (void)out_size; (void)ws_size;
  const float* x    = (const float*)d_in[0];
  const float* mem  = (const float*)d_in[1];
  const float* Wq   = (const float*)d_in[2];
  const float* bq   = (const float*)d_in[3];
  const float* Wk   = (const float*)d_in[4];
  const float* bk   = (const float*)d_in[5];
  const float* Wv   = (const float*)d_in[6];
  const float* bv   = (const float*)d_in[7];
  const float* Wo   = (const float*)d_in[8];
  const float* bo   = (const float*)d_in[9];
  const float* W1   = (const float*)d_in[10];
  const float* b1   = (const float*)d_in[11];
  const float* W2   = (const float*)d_in[12];
  const float* b2   = (const float*)d_in[13];
  const float* g_a  = (const float*)d_in[14];
  const float* bt_a = (const float*)d_in[15];
  const float* g_m  = (const float*)d_in[16];
  const float* bt_m = (const float*)d_in[17];
  float* out = (float*)d_out;

  char* ws = (char*)d_ws;
  size_t off = 0;
  auto carve = [&](size_t bytes) -> void* {
    void* p = ws + off;
    off = (off + bytes + 255) & ~(size_t)255;
    return p;
  };
  bf16*  wB    = (bf16*)carve(12582912L * 2);        // packed bf16 weights
  float* bqkv  = (float*)carve(3072 * 4);
  float* rtab  = (float*)carve(9216 * 2 * 4);        // rope cos/sin table
  bf16*  xa    = (bf16*)carve(4608L * 1024 * 2);     // LN1 out
  bf16*  qh    = (bf16*)carve(8L * 16 * 512 * 64 * 2);
  bf16*  kh    = (bf16*)carve(8L * 16 * 576 * 64 * 2);
  bf16*  vt    = (bf16*)carve(8L * 16 * 576 * 64 * 2);
  bf16*  attn  = (bf16*)carve(4096L * 1024 * 2);     // flash out, (B*T, D)
  bf16*  x2    = (bf16*)carve(4096L * 1024 * 2);     // post-attn residual bf16
  bf16*  xn    = (bf16*)carve(4096L * 1024 * 2);     // LN2 out
  bf16*  hbuf  = (bf16*)carve(4096L * 4096 * 2);     // relu^2 hidden
  bf16*  partsb= (bf16*)carve(4L * 4096 * 1024 * 2); // split-K bf16 partials

  // LN1 + {Wq,Wk,Wv convert, bias concat, rope table}
  ln_setup<<<7728, 256, 0, stream>>>(x, mem, g_a, bt_a, xa,
                                     Wq, Wk, Wv, bq, bk, bv, wB, bqkv, rtab);

  // QKV fused (bias+RoPE+reshape+Q-scale, V transposed): grid (12,18)
  gemm_qkv<<<dim3(12, 18, 1), 512, 0, stream>>>(xa, wB, bqkv, rtab, qh, kh, vt);

  // flash attention (1024 blocks) + Wo/W1/W2 conversion backfill (9216 blocks)
  flash_attn<<<10240, 256, 0, stream>>>(qh, kh, vt, attn,
                                        Wo, W1, W2, wB + 3145728L);

  // Wo split-K=4 (bf16 partials): (4096,1024)x(1024,1024)^T, slice K=256
  gemm_wo<<<dim3(4, 16, 4), 512, 0, stream>>>(attn, wB + 3145728L, partsb);
  // fused: x2(bf16) = sum(parts)+bo+x ; xn = LN
  reduce_ln<<<4096, 256, 0, stream>>>(partsb, bo, x, g_m, bt_m, x2, xn);

  // W1 + relu^2: (4096,1024)x(4096,1024)^T -> (4096,4096) bf16, grid (16,16)
  gemm_w1<<<dim3(16, 16, 1), 512, 0, stream>>>(xn, wB + 4194304L, b1, hbuf);

  // W2 split-K=4 (bf16 partials): (4096,4096)x(1024,4096)^T, slice K=1024
  gemm_w2<<<dim3(4, 16, 4), 512, 0, stream>>>(hbuf, wB + 8388608L, partsb);
  reduce_k<<<4096, 256, 0, stream>>>(partsb, b2, x2, out);
}